// Round 5
// baseline (414.301 us; speedup 1.0000x reference)
//
#include <hip/hip_runtime.h>
#include <hip/hip_bf16.h>

// Autoregressive LSTM: B=16384, T=60, D=34, E=128, H=64, n_seeds=10
// Persistent block = 32 batch rows x 60 steps, 4 waves, 512 blocks (2/CU).
// R5: swapped-operand MFMA (A=W, B=act) for gates/enc' (contiguous LDS epilogues);
// dec GEMM in normal orientation (A=h, B=W_dec) so global out stores are
// feature-in-lane -> 64B full-line writes (R4's batch-in-lane stores caused
// 4x write amplification via partial-line write-allocate).

typedef float f32x4 __attribute__((ext_vector_type(4)));
typedef float f32x2 __attribute__((ext_vector_type(2)));
typedef __bf16 bf16x8 __attribute__((ext_vector_type(8)));
typedef unsigned short u16x8 __attribute__((ext_vector_type(8)));
typedef unsigned short u16x4 __attribute__((ext_vector_type(4)));

#define MFMA_BF16(A, B, C) \
    __builtin_amdgcn_mfma_f32_16x16x32_bf16(__builtin_bit_cast(bf16x8, (A)), \
                                            __builtin_bit_cast(bf16x8, (B)), (C), 0, 0, 0)

__device__ __forceinline__ unsigned short f2b(float f) {
    return __builtin_bit_cast(unsigned short, (__bf16)f);
}
__device__ __forceinline__ float exp2_(float x) {
#if __has_builtin(__builtin_amdgcn_exp2f)
    return __builtin_amdgcn_exp2f(x);
#else
    return __exp2f(x);
#endif
}
__device__ __forceinline__ float rcp_(float x) {
    return __builtin_amdgcn_rcpf(x);
}
__device__ __forceinline__ float sig_(float x) {
    return rcp_(1.0f + exp2_(-1.44269504f * x));
}
__device__ __forceinline__ float tanh_(float x) {
    return __builtin_fmaf(2.0f, rcp_(1.0f + exp2_(-2.88539008f * x)), -1.0f);
}

__global__ __launch_bounds__(256, 2) void ar_lstm_kernel(
    const float* __restrict__ x,      // (16384,60,34)
    const float* __restrict__ W_enc,  // (128,34)
    const float* __restrict__ b_enc,  // (128)
    const float* __restrict__ W_ih,   // (256,128)
    const float* __restrict__ W_hh,   // (256,64)
    const float* __restrict__ b_ih,   // (256)
    const float* __restrict__ b_hh,   // (256)
    const float* __restrict__ W_dec,  // (34,64)
    const float* __restrict__ b_dec,  // (34)
    float* __restrict__ out)          // (16384,50,34)
{
    __shared__ __attribute__((aligned(16))) unsigned short x_s[32][136];    // rnn_in (M x 128)
    __shared__ __attribute__((aligned(16))) unsigned short h_s[2][32][72];  // h double-buffered
    __shared__ __attribute__((aligned(16))) unsigned short d_s[2][32][72];  // seed input staging
    __shared__ __attribute__((aligned(16))) float wdec_f[34][64];           // W_dec fp32 (init only)
    __shared__ float bdec_f[34];

    const int tid = threadIdx.x;
    const int w  = tid >> 6;   // wave 0..3
    const int l  = tid & 63;
    const int lr = l & 15;
    const int lg = l >> 4;
    const int b0 = blockIdx.x * 32;

    for (int i = tid; i < 32 * 136;    i += 256) (&x_s[0][0])[i] = 0;
    for (int i = tid; i < 2 * 32 * 72; i += 256) (&h_s[0][0][0])[i] = 0;
    for (int i = tid; i < 2 * 32 * 72; i += 256) (&d_s[0][0][0])[i] = 0;
    for (int i = tid; i < 34 * 64;     i += 256) (&wdec_f[0][0])[i] = W_dec[i];
    if (tid < 34) bdec_f[tid] = b_dec[tid];
    for (int e = tid; e < 32 * 34; e += 256) {
        int r = e / 34, d = e - r * 34;
        d_s[0][r][d] = f2b(x[((b0 + r) * 60 + 0) * 34 + d]);
    }

    // ---- weight fragments in registers (same contents serve A- or B-operand) ----
    u16x8 wg[4][6];
    for (int g = 0; g < 4; ++g) {
        int n = (w + 4 * g) * 16 + lr;
        for (int kt = 0; kt < 4; ++kt)
            for (int i = 0; i < 8; ++i)
                wg[g][kt][i] = f2b(W_ih[n * 128 + kt * 32 + lg * 8 + i]);
        for (int kt = 0; kt < 2; ++kt)
            for (int i = 0; i < 8; ++i)
                wg[g][4 + kt][i] = f2b(W_hh[n * 64 + kt * 32 + lg * 8 + i]);
    }
    u16x8 we[2][2];
    for (int ntl = 0; ntl < 2; ++ntl) {
        int n = (w * 2 + ntl) * 16 + lr;
        for (int kt = 0; kt < 2; ++kt)
            for (int i = 0; i < 8; ++i) {
                int k = kt * 32 + lg * 8 + i;
                we[ntl][kt][i] = (k < 34) ? f2b(W_enc[n * 34 + k]) : (unsigned short)0;
            }
    }
    u16x8 wd[2];
    {
        int n = w * 16 + lr;
        bool v = (w < 3) && (n < 34);
        for (int kt = 0; kt < 2; ++kt)
            for (int i = 0; i < 8; ++i)
                wd[kt][i] = v ? f2b(W_dec[n * 64 + kt * 32 + lg * 8 + i]) : (unsigned short)0;
    }

    // ---- biases ----
    // swapped-layout biases (features across acc regs): gates, enc, enc'
    f32x4 bias_gv[4];
    for (int g = 0; g < 4; ++g) {
        int nb = (w + 4 * g) * 16 + lg * 4;
        for (int r = 0; r < 4; ++r) bias_gv[g][r] = b_ih[nb + r] + b_hh[nb + r];
    }
    f32x4 bias_ev[2];
    for (int ntl = 0; ntl < 2; ++ntl) {
        int nb = (w * 2 + ntl) * 16 + lg * 4;
        for (int r = 0; r < 4; ++r) bias_ev[ntl][r] = b_enc[nb + r];
    }
    // normal-layout dec bias (feature = lane col nd)
    float bias_d = 0.0f;
    {
        int nd = w * 16 + lr;
        bias_d = (w < 3 && nd < 34) ? b_dec[nd] : 0.0f;
    }

    __syncthreads();

    // ---- fused W' = W_enc @ W_dec ----
    u16x8 wf[2][2];
    for (int ntl = 0; ntl < 2; ++ntl) {
        int n = (w * 2 + ntl) * 16 + lr;
        f32x4 av0 = {0,0,0,0}, av1 = {0,0,0,0}, av2 = {0,0,0,0}, av3 = {0,0,0,0};
        for (int j = 0; j < 34; ++j) {
            float wej = W_enc[n * 34 + j];
            av0 += wej * *(const f32x4*)&wdec_f[j][lg * 8];
            av1 += wej * *(const f32x4*)&wdec_f[j][lg * 8 + 4];
            av2 += wej * *(const f32x4*)&wdec_f[j][32 + lg * 8];
            av3 += wej * *(const f32x4*)&wdec_f[j][32 + lg * 8 + 4];
        }
        for (int i = 0; i < 4; ++i) {
            wf[ntl][0][i]     = f2b(av0[i]);
            wf[ntl][0][4 + i] = f2b(av1[i]);
            wf[ntl][1][i]     = f2b(av2[i]);
            wf[ntl][1][4 + i] = f2b(av3[i]);
        }
    }
    // bias' = b_enc + W_enc @ b_dec (swapped layout: rows nb+r)
    f32x4 bias_fv[2];
    for (int ntl = 0; ntl < 2; ++ntl) {
        int nb = (w * 2 + ntl) * 16 + lg * 4;
        for (int r = 0; r < 4; ++r) {
            float s = b_enc[nb + r];
            for (int j = 0; j < 34; ++j) s += W_enc[(nb + r) * 34 + j] * bdec_f[j];
            bias_fv[ntl][r] = s;
        }
    }

    // c state: swapped layout (batch = lr, features = lg*4+r)
    float c_st[2][4];
    // prev/out accumulator: NORMAL layout (batch = lg*4+r, feature col = w*16+lr)
    float prev[2][4];
    for (int mt = 0; mt < 2; ++mt)
        for (int r = 0; r < 4; ++r) { c_st[mt][r] = 0.0f; prev[mt][r] = 0.0f; }

    const int nd = w * 16 + lr;   // dec/out feature column for this lane

    for (int t = 0; t < 60; ++t) {
        const int hw = t & 1;
        const int hr = hw ^ 1;

        if (t < 10) {
            // seed encode (swapped): emb^T = W_enc @ x^T
            u16x8 bd[2][2];
            for (int mt = 0; mt < 2; ++mt)
                for (int kt = 0; kt < 2; ++kt)
                    bd[mt][kt] = *(const u16x8*)&d_s[hw][mt * 16 + lr][kt * 32 + lg * 8];
            for (int mt = 0; mt < 2; ++mt)
                for (int ntl = 0; ntl < 2; ++ntl) {
                    f32x4 a = bias_ev[ntl];
                    a = MFMA_BF16(we[ntl][0], bd[mt][0], a);
                    a = MFMA_BF16(we[ntl][1], bd[mt][1], a);
                    u16x4 pv;
                    for (int r = 0; r < 4; ++r) pv[r] = f2b(fmaxf(a[r], 0.0f));
                    *(u16x4*)&x_s[mt * 16 + lr][(w * 2 + ntl) * 16 + lg * 4] = pv;
                }
            if (t + 1 < 10)
                for (int e = tid; e < 32 * 34; e += 256) {
                    int r = e / 34, d = e - r * 34;
                    d_s[hr][r][d] = f2b(x[((b0 + r) * 60 + (t + 1)) * 34 + d]);
                }
            __syncthreads();
        }

        // ---- gates (swapped): G^T = [W_ih|W_hh] @ [x|h]^T, then cell ----
        for (int mt = 0; mt < 2; ++mt) {
            u16x8 bx[4], bh[2];
            for (int kt = 0; kt < 4; ++kt)
                bx[kt] = *(const u16x8*)&x_s[mt * 16 + lr][kt * 32 + lg * 8];
            for (int kt = 0; kt < 2; ++kt)
                bh[kt] = *(const u16x8*)&h_s[hr][mt * 16 + lr][kt * 32 + lg * 8];
            f32x4 acc[4];
            for (int g = 0; g < 4; ++g) {
                f32x4 a = bias_gv[g];
                a = MFMA_BF16(wg[g][0], bx[0], a);
                a = MFMA_BF16(wg[g][1], bx[1], a);
                a = MFMA_BF16(wg[g][2], bx[2], a);
                a = MFMA_BF16(wg[g][3], bx[3], a);
                a = MFMA_BF16(wg[g][4], bh[0], a);
                a = MFMA_BF16(wg[g][5], bh[1], a);
                acc[g] = a;
            }
            u16x4 hv;
            for (int r = 0; r < 4; ++r) {
                float cn = sig_(acc[1][r]) * c_st[mt][r] + sig_(acc[0][r]) * tanh_(acc[2][r]);
                float hn = sig_(acc[3][r]) * tanh_(cn);
                c_st[mt][r] = cn;
                hv[r] = f2b(hn);
            }
            *(u16x4*)&h_s[hw][mt * 16 + lr][w * 16 + lg * 4] = hv;
        }
        __syncthreads();

        if (t >= 9) {
            u16x8 bh2[2][2];
            for (int mt = 0; mt < 2; ++mt)
                for (int kt = 0; kt < 2; ++kt)
                    bh2[mt][kt] = *(const u16x8*)&h_s[hw][mt * 16 + lr][kt * 32 + lg * 8];

            if (t == 9) {
                // prev = x[:, 9, :] in NORMAL layout (batch = lg*4+r, col = nd)
                if (w < 3 && nd < 34)
                    for (int mt = 0; mt < 2; ++mt)
                        for (int r = 0; r < 4; ++r)
                            prev[mt][r] = x[((size_t)(b0 + mt * 16 + lg * 4 + r) * 60 + 9) * 34 + nd];
            } else if (w < 3) {
                // dec (normal orientation): A = h (bh2), B = W_dec (wd)
                // D: col = nd (feature in lanes), row = batch lg*4+r -> 64B stores
                for (int mt = 0; mt < 2; ++mt) {
                    f32x4 a = {bias_d, bias_d, bias_d, bias_d};
                    a = MFMA_BF16(bh2[mt][0], wd[0], a);
                    a = MFMA_BF16(bh2[mt][1], wd[1], a);
                    if (nd < 34)
                        for (int r = 0; r < 4; ++r) {
                            float o = a[r] + prev[mt][r];
                            prev[mt][r] = o;
                            out[((size_t)(b0 + mt * 16 + lg * 4 + r) * 50 + (t - 10)) * 34 + nd] = o;
                        }
                }
            }

            if (t < 59) {
                // enc' (swapped): rnn_in^T = relu(W' @ h^T + b')
                for (int mt = 0; mt < 2; ++mt)
                    for (int ntl = 0; ntl < 2; ++ntl) {
                        f32x4 a = bias_fv[ntl];
                        a = MFMA_BF16(wf[ntl][0], bh2[mt][0], a);
                        a = MFMA_BF16(wf[ntl][1], bh2[mt][1], a);
                        u16x4 pv;
                        for (int r = 0; r < 4; ++r) pv[r] = f2b(fmaxf(a[r], 0.0f));
                        *(u16x4*)&x_s[mt * 16 + lr][(w * 2 + ntl) * 16 + lg * 4] = pv;
                    }
            }
            __syncthreads();
        }
    }
}

extern "C" void kernel_launch(void* const* d_in, const int* in_sizes, int n_in,
                              void* d_out, int out_size, void* d_ws, size_t ws_size,
                              hipStream_t stream) {
    const float* x     = (const float*)d_in[0];
    const float* W_enc = (const float*)d_in[1];
    const float* b_enc = (const float*)d_in[2];
    const float* W_ih  = (const float*)d_in[3];
    const float* W_hh  = (const float*)d_in[4];
    const float* b_ih  = (const float*)d_in[5];
    const float* b_hh  = (const float*)d_in[6];
    const float* W_dec = (const float*)d_in[7];
    const float* b_dec = (const float*)d_in[8];
    float* out = (float*)d_out;
    // n_seeds (d_in[9]) is compile-time 10 for this problem shape.
    ar_lstm_kernel<<<512, 256, 0, stream>>>(x, W_enc, b_enc, W_ih, W_hh,
                                            b_ih, b_hh, W_dec, b_dec, out);
}

// Round 6
// 369.463 us; speedup vs baseline: 1.1214x; 1.1214x over previous
//
#include <hip/hip_runtime.h>
#include <hip/hip_bf16.h>

// Autoregressive LSTM: B=16384, T=60, D=34, E=128, H=64, n_seeds=10
// Persistent block = 32 batch rows x 60 steps, 4 waves, 512 blocks (2/CU).
// R6: R5 structure (swapped-operand gates/enc' + normal-orientation dec GEMM),
// minus ~24 persistent VGPRs: seed-enc weights moved to an LDS table, seed-enc
// bias loaded from global per seed step. Theory: R4/R5 regression was scratch
// spill traffic (FETCH 197MB / WRITE 482MB with identical global addressing
// to R3), not store coalescing.

typedef float f32x4 __attribute__((ext_vector_type(4)));
typedef __bf16 bf16x8 __attribute__((ext_vector_type(8)));
typedef unsigned short u16x8 __attribute__((ext_vector_type(8)));
typedef unsigned short u16x4 __attribute__((ext_vector_type(4)));

#define MFMA_BF16(A, B, C) \
    __builtin_amdgcn_mfma_f32_16x16x32_bf16(__builtin_bit_cast(bf16x8, (A)), \
                                            __builtin_bit_cast(bf16x8, (B)), (C), 0, 0, 0)

__device__ __forceinline__ unsigned short f2b(float f) {
    return __builtin_bit_cast(unsigned short, (__bf16)f);
}
__device__ __forceinline__ float exp2_(float x) {
#if __has_builtin(__builtin_amdgcn_exp2f)
    return __builtin_amdgcn_exp2f(x);
#else
    return __exp2f(x);
#endif
}
__device__ __forceinline__ float rcp_(float x) {
    return __builtin_amdgcn_rcpf(x);
}
__device__ __forceinline__ float sig_(float x) {
    return rcp_(1.0f + exp2_(-1.44269504f * x));
}
__device__ __forceinline__ float tanh_(float x) {
    return __builtin_fmaf(2.0f, rcp_(1.0f + exp2_(-2.88539008f * x)), -1.0f);
}

__global__ __launch_bounds__(256, 2) void ar_lstm_kernel(
    const float* __restrict__ x,      // (16384,60,34)
    const float* __restrict__ W_enc,  // (128,34)
    const float* __restrict__ b_enc,  // (128)
    const float* __restrict__ W_ih,   // (256,128)
    const float* __restrict__ W_hh,   // (256,64)
    const float* __restrict__ b_ih,   // (256)
    const float* __restrict__ b_hh,   // (256)
    const float* __restrict__ W_dec,  // (34,64)
    const float* __restrict__ b_dec,  // (34)
    float* __restrict__ out)          // (16384,50,34)
{
    __shared__ __attribute__((aligned(16))) unsigned short x_s[32][136];    // rnn_in (M x 128)
    __shared__ __attribute__((aligned(16))) unsigned short h_s[2][32][72];  // h double-buffered
    __shared__ __attribute__((aligned(16))) unsigned short d_s[2][32][72];  // seed input staging
    __shared__ __attribute__((aligned(16))) float wdec_f[34][64];           // W_dec fp32 (init only)
    __shared__ float bdec_f[34];
    // seed-enc weight fragments, one 16B slot per thread per (ntl,kt):
    // lane stride 16B -> conflict-free ds_read_b128
    __shared__ __attribute__((aligned(16))) u16x8 we_tab[4][256];

    const int tid = threadIdx.x;
    const int w  = tid >> 6;   // wave 0..3
    const int l  = tid & 63;
    const int lr = l & 15;
    const int lg = l >> 4;
    const int b0 = blockIdx.x * 32;

    for (int i = tid; i < 32 * 136;    i += 256) (&x_s[0][0])[i] = 0;
    for (int i = tid; i < 2 * 32 * 72; i += 256) (&h_s[0][0][0])[i] = 0;
    for (int i = tid; i < 2 * 32 * 72; i += 256) (&d_s[0][0][0])[i] = 0;
    for (int i = tid; i < 34 * 64;     i += 256) (&wdec_f[0][0])[i] = W_dec[i];
    if (tid < 34) bdec_f[tid] = b_dec[tid];
    for (int e = tid; e < 32 * 34; e += 256) {
        int r = e / 34, d = e - r * 34;
        d_s[0][r][d] = f2b(x[((b0 + r) * 60 + 0) * 34 + d]);
    }
    // seed-enc weight table (used only during the 10 seed steps)
    for (int ntl = 0; ntl < 2; ++ntl) {
        int n = (w * 2 + ntl) * 16 + lr;
        for (int kt = 0; kt < 2; ++kt) {
            u16x8 tmp;
            for (int i = 0; i < 8; ++i) {
                int k = kt * 32 + lg * 8 + i;
                tmp[i] = (k < 34) ? f2b(W_enc[n * 34 + k]) : (unsigned short)0;
            }
            we_tab[ntl * 2 + kt][tid] = tmp;
        }
    }

    // ---- persistent weight fragments in registers ----
    u16x8 wg[4][6];
    for (int g = 0; g < 4; ++g) {
        int n = (w + 4 * g) * 16 + lr;
        for (int kt = 0; kt < 4; ++kt)
            for (int i = 0; i < 8; ++i)
                wg[g][kt][i] = f2b(W_ih[n * 128 + kt * 32 + lg * 8 + i]);
        for (int kt = 0; kt < 2; ++kt)
            for (int i = 0; i < 8; ++i)
                wg[g][4 + kt][i] = f2b(W_hh[n * 64 + kt * 32 + lg * 8 + i]);
    }
    u16x8 wd[2];
    {
        int n = w * 16 + lr;
        bool v = (w < 3) && (n < 34);
        for (int kt = 0; kt < 2; ++kt)
            for (int i = 0; i < 8; ++i)
                wd[kt][i] = v ? f2b(W_dec[n * 64 + kt * 32 + lg * 8 + i]) : (unsigned short)0;
    }

    // ---- biases ----
    f32x4 bias_gv[4];   // swapped layout: features across acc regs
    for (int g = 0; g < 4; ++g) {
        int nb = (w + 4 * g) * 16 + lg * 4;
        for (int r = 0; r < 4; ++r) bias_gv[g][r] = b_ih[nb + r] + b_hh[nb + r];
    }
    float bias_d = 0.0f;  // normal layout: feature = lane col nd
    {
        int nd_ = w * 16 + lr;
        bias_d = (w < 3 && nd_ < 34) ? b_dec[nd_] : 0.0f;
    }

    __syncthreads();

    // ---- fused W' = W_enc @ W_dec ----
    u16x8 wf[2][2];
    for (int ntl = 0; ntl < 2; ++ntl) {
        int n = (w * 2 + ntl) * 16 + lr;
        f32x4 av0 = {0,0,0,0}, av1 = {0,0,0,0}, av2 = {0,0,0,0}, av3 = {0,0,0,0};
        for (int j = 0; j < 34; ++j) {
            float wej = W_enc[n * 34 + j];
            av0 += wej * *(const f32x4*)&wdec_f[j][lg * 8];
            av1 += wej * *(const f32x4*)&wdec_f[j][lg * 8 + 4];
            av2 += wej * *(const f32x4*)&wdec_f[j][32 + lg * 8];
            av3 += wej * *(const f32x4*)&wdec_f[j][32 + lg * 8 + 4];
        }
        for (int i = 0; i < 4; ++i) {
            wf[ntl][0][i]     = f2b(av0[i]);
            wf[ntl][0][4 + i] = f2b(av1[i]);
            wf[ntl][1][i]     = f2b(av2[i]);
            wf[ntl][1][4 + i] = f2b(av3[i]);
        }
    }
    // bias' = b_enc + W_enc @ b_dec (swapped layout: rows nb+r)
    f32x4 bias_fv[2];
    for (int ntl = 0; ntl < 2; ++ntl) {
        int nb = (w * 2 + ntl) * 16 + lg * 4;
        for (int r = 0; r < 4; ++r) {
            float s = b_enc[nb + r];
            for (int j = 0; j < 34; ++j) s += W_enc[(nb + r) * 34 + j] * bdec_f[j];
            bias_fv[ntl][r] = s;
        }
    }

    // c state: swapped layout (batch = lr, features = lg*4+r)
    float c_st[2][4];
    // prev/out accumulator: normal layout (batch = lg*4+r, feature col = w*16+lr)
    float prev[2][4];
    for (int mt = 0; mt < 2; ++mt)
        for (int r = 0; r < 4; ++r) { c_st[mt][r] = 0.0f; prev[mt][r] = 0.0f; }

    const int nd = w * 16 + lr;   // dec/out feature column for this lane

    for (int t = 0; t < 60; ++t) {
        const int hw = t & 1;
        const int hr = hw ^ 1;

        if (t < 10) {
            // seed encode (swapped): emb^T = W_enc @ x^T; weights from LDS table
            u16x8 wet[2][2];
            wet[0][0] = we_tab[0][tid];
            wet[0][1] = we_tab[1][tid];
            wet[1][0] = we_tab[2][tid];
            wet[1][1] = we_tab[3][tid];
            u16x8 bd[2][2];
            for (int mt = 0; mt < 2; ++mt)
                for (int kt = 0; kt < 2; ++kt)
                    bd[mt][kt] = *(const u16x8*)&d_s[hw][mt * 16 + lr][kt * 32 + lg * 8];
            for (int mt = 0; mt < 2; ++mt)
                for (int ntl = 0; ntl < 2; ++ntl) {
                    f32x4 a = *(const f32x4*)&b_enc[(w * 2 + ntl) * 16 + lg * 4];
                    a = MFMA_BF16(wet[ntl][0], bd[mt][0], a);
                    a = MFMA_BF16(wet[ntl][1], bd[mt][1], a);
                    u16x4 pv;
                    for (int r = 0; r < 4; ++r) pv[r] = f2b(fmaxf(a[r], 0.0f));
                    *(u16x4*)&x_s[mt * 16 + lr][(w * 2 + ntl) * 16 + lg * 4] = pv;
                }
            if (t + 1 < 10)
                for (int e = tid; e < 32 * 34; e += 256) {
                    int r = e / 34, d = e - r * 34;
                    d_s[hr][r][d] = f2b(x[((b0 + r) * 60 + (t + 1)) * 34 + d]);
                }
            __syncthreads();
        }

        // ---- gates (swapped): G^T = [W_ih|W_hh] @ [x|h]^T, then cell ----
        for (int mt = 0; mt < 2; ++mt) {
            u16x8 bx[4], bh[2];
            for (int kt = 0; kt < 4; ++kt)
                bx[kt] = *(const u16x8*)&x_s[mt * 16 + lr][kt * 32 + lg * 8];
            for (int kt = 0; kt < 2; ++kt)
                bh[kt] = *(const u16x8*)&h_s[hr][mt * 16 + lr][kt * 32 + lg * 8];
            f32x4 acc[4];
            for (int g = 0; g < 4; ++g) {
                f32x4 a = bias_gv[g];
                a = MFMA_BF16(wg[g][0], bx[0], a);
                a = MFMA_BF16(wg[g][1], bx[1], a);
                a = MFMA_BF16(wg[g][2], bx[2], a);
                a = MFMA_BF16(wg[g][3], bx[3], a);
                a = MFMA_BF16(wg[g][4], bh[0], a);
                a = MFMA_BF16(wg[g][5], bh[1], a);
                acc[g] = a;
            }
            u16x4 hv;
            for (int r = 0; r < 4; ++r) {
                float cn = sig_(acc[1][r]) * c_st[mt][r] + sig_(acc[0][r]) * tanh_(acc[2][r]);
                float hn = sig_(acc[3][r]) * tanh_(cn);
                c_st[mt][r] = cn;
                hv[r] = f2b(hn);
            }
            *(u16x4*)&h_s[hw][mt * 16 + lr][w * 16 + lg * 4] = hv;
        }
        __syncthreads();

        if (t >= 9) {
            u16x8 bh2[2][2];
            for (int mt = 0; mt < 2; ++mt)
                for (int kt = 0; kt < 2; ++kt)
                    bh2[mt][kt] = *(const u16x8*)&h_s[hw][mt * 16 + lr][kt * 32 + lg * 8];

            if (t == 9) {
                // prev = x[:, 9, :] in normal layout (batch = lg*4+r, col = nd)
                if (w < 3 && nd < 34)
                    for (int mt = 0; mt < 2; ++mt)
                        for (int r = 0; r < 4; ++r)
                            prev[mt][r] = x[((size_t)(b0 + mt * 16 + lg * 4 + r) * 60 + 9) * 34 + nd];
            } else if (w < 3) {
                // dec (normal orientation): A = h, B = W_dec -> feature-in-lane stores
                for (int mt = 0; mt < 2; ++mt) {
                    f32x4 a = {bias_d, bias_d, bias_d, bias_d};
                    a = MFMA_BF16(bh2[mt][0], wd[0], a);
                    a = MFMA_BF16(bh2[mt][1], wd[1], a);
                    if (nd < 34)
                        for (int r = 0; r < 4; ++r) {
                            float o = a[r] + prev[mt][r];
                            prev[mt][r] = o;
                            out[((size_t)(b0 + mt * 16 + lg * 4 + r) * 50 + (t - 10)) * 34 + nd] = o;
                        }
                }
            }

            if (t < 59) {
                // enc' (swapped): rnn_in^T = relu(W' @ h^T + b')
                for (int mt = 0; mt < 2; ++mt)
                    for (int ntl = 0; ntl < 2; ++ntl) {
                        f32x4 a = bias_fv[ntl];
                        a = MFMA_BF16(wf[ntl][0], bh2[mt][0], a);
                        a = MFMA_BF16(wf[ntl][1], bh2[mt][1], a);
                        u16x4 pv;
                        for (int r = 0; r < 4; ++r) pv[r] = f2b(fmaxf(a[r], 0.0f));
                        *(u16x4*)&x_s[mt * 16 + lr][(w * 2 + ntl) * 16 + lg * 4] = pv;
                    }
            }
            __syncthreads();
        }
    }
}

extern "C" void kernel_launch(void* const* d_in, const int* in_sizes, int n_in,
                              void* d_out, int out_size, void* d_ws, size_t ws_size,
                              hipStream_t stream) {
    const float* x     = (const float*)d_in[0];
    const float* W_enc = (const float*)d_in[1];
    const float* b_enc = (const float*)d_in[2];
    const float* W_ih  = (const float*)d_in[3];
    const float* W_hh  = (const float*)d_in[4];
    const float* b_ih  = (const float*)d_in[5];
    const float* b_hh  = (const float*)d_in[6];
    const float* W_dec = (const float*)d_in[7];
    const float* b_dec = (const float*)d_in[8];
    float* out = (float*)d_out;
    // n_seeds (d_in[9]) is compile-time 10 for this problem shape.
    ar_lstm_kernel<<<512, 256, 0, stream>>>(x, W_enc, b_enc, W_ih, W_hh,
                                            b_ih, b_hh, W_dec, b_dec, out);
}

// Round 7
// 207.787 us; speedup vs baseline: 1.9939x; 1.7781x over previous
//
#include <hip/hip_runtime.h>
#include <hip/hip_bf16.h>

// Autoregressive LSTM: B=16384, T=60, D=34, E=128, H=64, n_seeds=10
// Persistent block = 32 batch rows x 60 steps, 4 waves, 512 blocks (2/CU).
// R7: revert to R3 (known-good: 213us, FETCH 14MB, WRITE 112MB). R4-R6's
// swapped-operand bundle produced ~340MB of mystery scratch writes; abandoned.
// On top of R3: (1) gates MFMA for both m-tiles issued as one 12-MFMA cluster
// before the cell epilogues (explicit ILP), (2) s_setprio(1) around it.

typedef float f32x4 __attribute__((ext_vector_type(4)));
typedef __bf16 bf16x8 __attribute__((ext_vector_type(8)));
typedef unsigned short u16x8 __attribute__((ext_vector_type(8)));

#define MFMA_BF16(A, B, C) \
    __builtin_amdgcn_mfma_f32_16x16x32_bf16(__builtin_bit_cast(bf16x8, (A)), \
                                            __builtin_bit_cast(bf16x8, (B)), (C), 0, 0, 0)

__device__ __forceinline__ unsigned short f2b(float f) {
    return __builtin_bit_cast(unsigned short, (__bf16)f);
}
__device__ __forceinline__ float exp2_(float x) {
#if __has_builtin(__builtin_amdgcn_exp2f)
    return __builtin_amdgcn_exp2f(x);
#else
    return __exp2f(x);
#endif
}
__device__ __forceinline__ float rcp_(float x) {
    return __builtin_amdgcn_rcpf(x);
}
__device__ __forceinline__ float sig_(float x) {
    return rcp_(1.0f + exp2_(-1.44269504f * x));
}
__device__ __forceinline__ float tanh_(float x) {
    return __builtin_fmaf(2.0f, rcp_(1.0f + exp2_(-2.88539008f * x)), -1.0f);
}

__global__ __launch_bounds__(256, 2) void ar_lstm_kernel(
    const float* __restrict__ x,      // (16384,60,34)
    const float* __restrict__ W_enc,  // (128,34)
    const float* __restrict__ b_enc,  // (128)
    const float* __restrict__ W_ih,   // (256,128)
    const float* __restrict__ W_hh,   // (256,64)
    const float* __restrict__ b_ih,   // (256)
    const float* __restrict__ b_hh,   // (256)
    const float* __restrict__ W_dec,  // (34,64)
    const float* __restrict__ b_dec,  // (34)
    float* __restrict__ out)          // (16384,50,34)
{
    // +8 u16 row pad => 16B bank rotation; 2-way conflicts only (free).
    __shared__ __attribute__((aligned(16))) unsigned short x_s[32][136];    // rnn_in (M x 128)
    __shared__ __attribute__((aligned(16))) unsigned short h_s[2][32][72];  // h double-buffered
    __shared__ __attribute__((aligned(16))) unsigned short d_s[2][32][72];  // seed input staging
    __shared__ __attribute__((aligned(16))) float wdec_f[34][64];           // W_dec fp32 (init only)
    __shared__ float bdec_f[34];

    const int tid = threadIdx.x;
    const int w  = tid >> 6;   // wave 0..3
    const int l  = tid & 63;
    const int lr = l & 15;     // A-row / B-col / D-col lane index
    const int lg = l >> 4;     // lane group 0..3
    const int b0 = blockIdx.x * 32;

    for (int i = tid; i < 32 * 136;    i += 256) (&x_s[0][0])[i] = 0;
    for (int i = tid; i < 2 * 32 * 72; i += 256) (&h_s[0][0][0])[i] = 0;
    for (int i = tid; i < 2 * 32 * 72; i += 256) (&d_s[0][0][0])[i] = 0;
    for (int i = tid; i < 34 * 64;     i += 256) (&wdec_f[0][0])[i] = W_dec[i];
    if (tid < 34) bdec_f[tid] = b_dec[tid];
    // stage seed frame t=0
    for (int e = tid; e < 32 * 34; e += 256) {
        int r = e / 34, d = e - r * 34;
        d_s[0][r][d] = f2b(x[((b0 + r) * 60 + 0) * 34 + d]);
    }

    // ---- weight fragments in registers ----
    // gates: wave w owns hidden cols j = w*16+lr for all 4 gates (n-tiles w+4g)
    u16x8 wg[4][6];
    float bias_g[4];
    for (int g = 0; g < 4; ++g) {
        int n = (w + 4 * g) * 16 + lr;
        bias_g[g] = b_ih[n] + b_hh[n];
        for (int kt = 0; kt < 4; ++kt)
            for (int i = 0; i < 8; ++i)
                wg[g][kt][i] = f2b(W_ih[n * 128 + kt * 32 + lg * 8 + i]);
        for (int kt = 0; kt < 2; ++kt)
            for (int i = 0; i < 8; ++i)
                wg[g][4 + kt][i] = f2b(W_hh[n * 64 + kt * 32 + lg * 8 + i]);
    }
    // seed encoder (K=34 zero-padded to 64)
    u16x8 we[2][2];
    float bias_e[2];
    for (int ntl = 0; ntl < 2; ++ntl) {
        int n = (w * 2 + ntl) * 16 + lr;
        bias_e[ntl] = b_enc[n];
        for (int kt = 0; kt < 2; ++kt)
            for (int i = 0; i < 8; ++i) {
                int k = kt * 32 + lg * 8 + i;
                we[ntl][kt][i] = (k < 34) ? f2b(W_enc[n * 34 + k]) : (unsigned short)0;
            }
    }
    // decoder (cols >= 34 zero; wave 3 never used)
    u16x8 wd[2];
    float bias_d = 0.0f;
    {
        int n = w * 16 + lr;
        bool v = (w < 3) && (n < 34);
        bias_d = v ? b_dec[n] : 0.0f;
        for (int kt = 0; kt < 2; ++kt)
            for (int i = 0; i < 8; ++i)
                wd[kt][i] = v ? f2b(W_dec[n * 64 + kt * 32 + lg * 8 + i]) : (unsigned short)0;
    }

    __syncthreads();  // wdec_f/bdec_f staged, LDS zeroed, d_s[0] staged

    // ---- fused W' = W_enc @ W_dec (128x64), b' = b_enc + W_enc @ b_dec ----
    u16x8 wf[2][2];
    float bias_f[2];
    for (int ntl = 0; ntl < 2; ++ntl) {
        int n = (w * 2 + ntl) * 16 + lr;
        f32x4 av0 = {0,0,0,0}, av1 = {0,0,0,0}, av2 = {0,0,0,0}, av3 = {0,0,0,0};
        float bacc = b_enc[n];
        for (int j = 0; j < 34; ++j) {
            float wej = W_enc[n * 34 + j];
            bacc += wej * bdec_f[j];
            av0 += wej * *(const f32x4*)&wdec_f[j][lg * 8];
            av1 += wej * *(const f32x4*)&wdec_f[j][lg * 8 + 4];
            av2 += wej * *(const f32x4*)&wdec_f[j][32 + lg * 8];
            av3 += wej * *(const f32x4*)&wdec_f[j][32 + lg * 8 + 4];
        }
        bias_f[ntl] = bacc;
        for (int i = 0; i < 4; ++i) {
            wf[ntl][0][i]     = f2b(av0[i]);
            wf[ntl][0][4 + i] = f2b(av1[i]);
            wf[ntl][1][i]     = f2b(av2[i]);
            wf[ntl][1][4 + i] = f2b(av3[i]);
        }
    }

    float c_st[2][4], prev[2][4];
    for (int mt = 0; mt < 2; ++mt)
        for (int r = 0; r < 4; ++r) { c_st[mt][r] = 0.0f; prev[mt][r] = 0.0f; }

    for (int t = 0; t < 60; ++t) {
        const int hw = t & 1;       // cell writes h_s[hw]
        const int hr = hw ^ 1;      // gates read h_s[hr]

        if (t < 10) {
            // seed encode: x_s = relu(d_s[hw] @ we^T); prefetch next seed frame
            u16x8 ad[2][2];
            for (int mt = 0; mt < 2; ++mt)
                for (int kt = 0; kt < 2; ++kt)
                    ad[mt][kt] = *(const u16x8*)&d_s[hw][mt * 16 + lr][kt * 32 + lg * 8];
            for (int mt = 0; mt < 2; ++mt)
                for (int ntl = 0; ntl < 2; ++ntl) {
                    f32x4 a = {bias_e[ntl], bias_e[ntl], bias_e[ntl], bias_e[ntl]};
                    a = MFMA_BF16(ad[mt][0], we[ntl][0], a);
                    a = MFMA_BF16(ad[mt][1], we[ntl][1], a);
                    for (int r = 0; r < 4; ++r)
                        x_s[mt * 16 + lg * 4 + r][(w * 2 + ntl) * 16 + lr] = f2b(fmaxf(a[r], 0.0f));
                }
            if (t + 1 < 10)
                for (int e = tid; e < 32 * 34; e += 256) {
                    int r = e / 34, d = e - r * 34;
                    d_s[hr][r][d] = f2b(x[((b0 + r) * 60 + (t + 1)) * 34 + d]);
                }
            __syncthreads();
        }

        // ---- gates GEMM: both m-tiles issued as one MFMA cluster ----
        u16x8 ax[2][4], ah[2][2];
        for (int mt = 0; mt < 2; ++mt) {
            for (int kt = 0; kt < 4; ++kt)
                ax[mt][kt] = *(const u16x8*)&x_s[mt * 16 + lr][kt * 32 + lg * 8];
            for (int kt = 0; kt < 2; ++kt)
                ah[mt][kt] = *(const u16x8*)&h_s[hr][mt * 16 + lr][kt * 32 + lg * 8];
        }
        f32x4 acc[2][4];
        __builtin_amdgcn_s_setprio(1);
        for (int mt = 0; mt < 2; ++mt)
            for (int g = 0; g < 4; ++g) {
                f32x4 a = {bias_g[g], bias_g[g], bias_g[g], bias_g[g]};
                a = MFMA_BF16(ax[mt][0], wg[g][0], a);
                a = MFMA_BF16(ax[mt][1], wg[g][1], a);
                a = MFMA_BF16(ax[mt][2], wg[g][2], a);
                a = MFMA_BF16(ax[mt][3], wg[g][3], a);
                a = MFMA_BF16(ah[mt][0], wg[g][4], a);
                a = MFMA_BF16(ah[mt][1], wg[g][5], a);
                acc[mt][g] = a;
            }
        __builtin_amdgcn_s_setprio(0);
        // ---- elementwise LSTM cell (fp32 c-state in registers) ----
        for (int mt = 0; mt < 2; ++mt)
            for (int r = 0; r < 4; ++r) {
                float cn = sig_(acc[mt][1][r]) * c_st[mt][r] + sig_(acc[mt][0][r]) * tanh_(acc[mt][2][r]);
                float hn = sig_(acc[mt][3][r]) * tanh_(cn);
                c_st[mt][r] = cn;
                h_s[hw][mt * 16 + lg * 4 + r][w * 16 + lr] = f2b(hn);
            }
        __syncthreads();

        if (t >= 9) {
            // dec (out) + fused enc' (next rnn_in), both from h_s[hw] A-frags
            u16x8 ah2[2][2];
            for (int mt = 0; mt < 2; ++mt)
                for (int kt = 0; kt < 2; ++kt)
                    ah2[mt][kt] = *(const u16x8*)&h_s[hw][mt * 16 + lr][kt * 32 + lg * 8];
            const int nd = w * 16 + lr;
            if (t == 9) {
                if (w < 3 && nd < 34)
                    for (int mt = 0; mt < 2; ++mt)
                        for (int r = 0; r < 4; ++r)
                            prev[mt][r] = x[((b0 + mt * 16 + lg * 4 + r) * 60 + 9) * 34 + nd];
            } else if (w < 3) {
                for (int mt = 0; mt < 2; ++mt) {
                    f32x4 a = {bias_d, bias_d, bias_d, bias_d};
                    a = MFMA_BF16(ah2[mt][0], wd[0], a);
                    a = MFMA_BF16(ah2[mt][1], wd[1], a);
                    if (nd < 34)
                        for (int r = 0; r < 4; ++r) {
                            float o = a[r] + prev[mt][r];
                            prev[mt][r] = o;
                            out[((b0 + mt * 16 + lg * 4 + r) * 50 + (t - 10)) * 34 + nd] = o;
                        }
                }
            }
            if (t < 59) {
                for (int mt = 0; mt < 2; ++mt)
                    for (int ntl = 0; ntl < 2; ++ntl) {
                        f32x4 a = {bias_f[ntl], bias_f[ntl], bias_f[ntl], bias_f[ntl]};
                        a = MFMA_BF16(ah2[mt][0], wf[ntl][0], a);
                        a = MFMA_BF16(ah2[mt][1], wf[ntl][1], a);
                        for (int r = 0; r < 4; ++r)
                            x_s[mt * 16 + lg * 4 + r][(w * 2 + ntl) * 16 + lr] = f2b(fmaxf(a[r], 0.0f));
                    }
            }
            __syncthreads();
        }
    }
}

extern "C" void kernel_launch(void* const* d_in, const int* in_sizes, int n_in,
                              void* d_out, int out_size, void* d_ws, size_t ws_size,
                              hipStream_t stream) {
    const float* x     = (const float*)d_in[0];
    const float* W_enc = (const float*)d_in[1];
    const float* b_enc = (const float*)d_in[2];
    const float* W_ih  = (const float*)d_in[3];
    const float* W_hh  = (const float*)d_in[4];
    const float* b_ih  = (const float*)d_in[5];
    const float* b_hh  = (const float*)d_in[6];
    const float* W_dec = (const float*)d_in[7];
    const float* b_dec = (const float*)d_in[8];
    float* out = (float*)d_out;
    // n_seeds (d_in[9]) is compile-time 10 for this problem shape.
    ar_lstm_kernel<<<512, 256, 0, stream>>>(x, W_enc, b_enc, W_ih, W_hh,
                                            b_ih, b_hh, W_dec, b_dec, out);
}